// Round 8
// baseline (185.727 us; speedup 1.0000x reference)
//
#include <hip/hip_runtime.h>
#include <hip/hip_bf16.h>
#include <math.h>

#define B_ROWS 8192
#define NEXP 16

typedef __attribute__((ext_vector_type(8))) short short8;
typedef __attribute__((ext_vector_type(4))) float f32x4;

__device__ __forceinline__ float softplus_f(float x) {
    return fmaxf(x, 0.f) + log1pf(expf(-fabsf(x)));
}

__device__ __forceinline__ float bf2f(short u) {
    union { unsigned int i; float f; } c;
    c.i = ((unsigned int)(unsigned short)u) << 16;
    return c.f;
}

__device__ __forceinline__ short f2bf_s(float x) {
    __hip_bfloat16 h = __float2bfloat16(x);
    return *(short*)&h;
}

__device__ __forceinline__ void gll16(const void* g, void* l) {
    __builtin_amdgcn_global_load_lds(
        (const __attribute__((address_space(1))) void*)g,
        (__attribute__((address_space(3))) void*)l, 16, 0, 0);
}

#define FENCE() asm volatile("" ::: "memory")
#define VM4 asm volatile("s_waitcnt vmcnt(4)" ::: "memory")
#define VM0 asm volatile("s_waitcnt vmcnt(0)" ::: "memory")
#define BAR __builtin_amdgcn_s_barrier()

// ================= UBER PREP v4 ============================================
// Aux roles (biasfold, W2 swizzle) moved into gemm3s tail; prep is now the
// pure bulk: WgT partials + casts/permutes. Grid 2944.
// [0,64)        WgT split-K partials (ct = b&7, ks = b>>3)
// [64,1088)     y cast (8 float4/thread)
// [1088,2112)   Mt2 permute
// [2112,2624)   W1yt tcast
// [2624,2656)   W1m2 zero-padded tcast
// [2656,2912)   W0p prep
// [2912,2944)   l0wyt tcast
__global__ __launch_bounds__(256) void prep_all(
    const float* __restrict__ y, const float* __restrict__ M,
    const float* __restrict__ lW1, const float* __restrict__ gw0,
    const float* __restrict__ l0w, const float* __restrict__ gw1,
    __hip_bfloat16* __restrict__ yb, short* __restrict__ Mt2,
    __hip_bfloat16* __restrict__ W1yt, short* __restrict__ W1m2,
    __hip_bfloat16* __restrict__ W0p, __hip_bfloat16* __restrict__ l0wyt,
    float* __restrict__ wgtp)
{
    __shared__ __align__(16) char smem[33280];
    const int b = blockIdx.x;
    const int tid = threadIdx.x;
    const int lane = tid & 63, w = tid >> 6;

    if (b < 64) {
        // ---- WgT split-K partial: P_ks[c][j] = sum_{o in ks*128..+128}
        //      l0w[(1024+o)*128+c] * gw1[j*1024+o], f32 out ----
        short* As = (short*)smem;
        short* Bs = (short*)(smem + 16384);
        const int ct = b & 7, ks = b >> 3;
        const int bn = ct * 128;
        const int wr = w >> 1, wc = w & 1;
        const int l15 = lane & 15, l4 = lane >> 4;

        f32x4 acc4[4][4] = {};
        for (int kq = 0; kq < 2; ++kq) {
            const int k0 = ks * 128 + kq * 64;
            {   // stage A: transpose-cast into swizzled image
                int c4 = (tid & 31) * 4;
                int kkr0 = tid >> 5;
                #pragma unroll
                for (int r = 0; r < 8; ++r) {
                    int kk = r * 8 + kkr0;
                    float4 v = *(const float4*)&l0w[(long)(1024 + k0 + kk) * 128 + c4];
                    int g = kk >> 3, sub = kk & 7;
                    #pragma unroll
                    for (int i = 0; i < 4; ++i) {
                        int row = c4 + i;
                        As[row * 64 + (g ^ (row & 7)) * 8 + sub] = f2bf_s(((const float*)&v)[i]);
                    }
                }
            }
            {   // stage B: row-cast into swizzled image
                int jr0 = tid >> 3;
                int g = tid & 7;
                #pragma unroll
                for (int s = 0; s < 4; ++s) {
                    int jrel = s * 32 + jr0;
                    const float* src = &gw1[(long)(bn + jrel) * 1024 + k0 + g * 8];
                    float4 v0 = *(const float4*)src;
                    float4 v1 = *(const float4*)(src + 4);
                    union { short8 v; short sh[8]; } o;
                    o.sh[0] = f2bf_s(v0.x); o.sh[1] = f2bf_s(v0.y);
                    o.sh[2] = f2bf_s(v0.z); o.sh[3] = f2bf_s(v0.w);
                    o.sh[4] = f2bf_s(v1.x); o.sh[5] = f2bf_s(v1.y);
                    o.sh[6] = f2bf_s(v1.z); o.sh[7] = f2bf_s(v1.w);
                    *(short8*)&Bs[jrel * 64 + (g ^ (jrel & 7)) * 8] = o.v;
                }
            }
            __syncthreads();
            #pragma unroll
            for (int st = 0; st < 2; ++st) {
                const int gr = (st * 4 + l4) ^ (l15 & 7);
                short8 a[4], bv[4];
                #pragma unroll
                for (int m = 0; m < 4; ++m)
                    a[m] = *(const short8*)&As[(wr * 64 + m * 16 + l15) * 64 + gr * 8];
                #pragma unroll
                for (int n = 0; n < 4; ++n)
                    bv[n] = *(const short8*)&Bs[(wc * 64 + n * 16 + l15) * 64 + gr * 8];
                #pragma unroll
                for (int m = 0; m < 4; ++m)
                    #pragma unroll
                    for (int n = 0; n < 4; ++n)
                        acc4[m][n] = __builtin_amdgcn_mfma_f32_16x16x32_bf16(a[m], bv[n], acc4[m][n], 0, 0, 0);
            }
            __syncthreads();
        }
        #pragma unroll
        for (int m = 0; m < 4; ++m) {
            int row = wr * 64 + m * 16 + l4 * 4;
            #pragma unroll
            for (int n = 0; n < 4; ++n) {
                int col = bn + wc * 64 + n * 16 + l15;
                #pragma unroll
                for (int r = 0; r < 4; ++r)
                    wgtp[((long)ks * 128 + row + r) * 1024 + col] = acc4[m][n][r];
            }
        }
        return;
    }

    if (b < 1088) {
        // ---- y cast: 1024 blocks, 8 float4 per thread (32 KB/block) ----
        const long base = (long)(b - 64) * 2048;
        #pragma unroll
        for (int j = 0; j < 8; ++j) {
            long i = base + j * 256 + tid;
            float4 v = ((const float4*)y)[i];
            union { ushort4 u; __hip_bfloat16 h[4]; } p;
            p.h[0] = __float2bfloat16(v.x);
            p.h[1] = __float2bfloat16(v.y);
            p.h[2] = __float2bfloat16(v.z);
            p.h[3] = __float2bfloat16(v.w);
            ((ushort4*)yb)[i] = p.u;
        }
        return;
    }

    if (b < 2112) {
        // ---- Mt2 permute ----
        short* t = (short*)smem;
        const long r0 = (long)(b - 1088) * 8;
        #pragma unroll
        for (int i = 0; i < 8; ++i) {
            int idx = i * 1024 + tid * 4;
            float4 v = *(const float4*)&M[r0 * 1024 + idx];
            short4 s;
            s.x = f2bf_s(v.x); s.y = f2bf_s(v.y); s.z = f2bf_s(v.z); s.w = f2bf_s(v.w);
            *(short4*)&t[idx] = s;
        }
        __syncthreads();
        const int e = tid & 15, rr = (tid >> 4) & 7, hf = tid >> 7;
        #pragma unroll
        for (int c = 0; c < 4; ++c) {
            union { short8 v; short s[8]; } o;
            #pragma unroll
            for (int j = 0; j < 8; ++j)
                o.s[j] = t[rr * 1024 + (hf * 32 + c * 8 + j) * 16 + e];
            *(short8*)&Mt2[(long)(e >> 1) * (8192L * 128) + (r0 + rr) * 128
                           + (e & 1) * 64 + hf * 32 + c * 8] = o.v;
        }
        return;
    }

    float (*t)[129] = (float(*)[129])smem;

    if (b < 2624) {
        int l = b - 2112, bx = l & 15, by = l >> 4;
        int n0 = bx * 128, k0 = by * 32;
        long base = 64L * 128 + (long)bx * (1088L * 128);
        #pragma unroll
        for (int ll = 0; ll < 16; ++ll) {
            int idx = tid + ll * 256;
            int kk = idx >> 7, nn = idx & 127;
            t[kk][nn] = lW1[base + (long)(k0 + kk) * 128 + nn];
        }
        __syncthreads();
        int nn = tid >> 1, kb = (tid & 1) * 16;
        #pragma unroll
        for (int j = 0; j < 16; ++j)
            W1yt[(long)(n0 + nn) * 1024 + k0 + kb + j] = __float2bfloat16(t[kb + j][nn]);
        return;
    }

    if (b < 2656) {
        int l = b - 2624, bx = l & 15, by = l >> 4;
        int n0 = bx * 128, k0 = by * 32;
        long base = (long)bx * (1088L * 128);
        #pragma unroll
        for (int ll = 0; ll < 16; ++ll) {
            int idx = tid + ll * 256;
            int kk = idx >> 7, nn = idx & 127;
            if (kk < 32) t[kk][nn] = lW1[base + (long)(k0 + kk) * 128 + nn];
        }
        __syncthreads();
        int nn = tid >> 1, kb = (tid & 1) * 16;
        int half = bx & 1;
        #pragma unroll
        for (int j = 0; j < 16; ++j) {
            W1m2[(long)(n0 + nn) * 128 + half * 64 + k0 + kb + j] = f2bf_s(t[kb + j][nn]);
            W1m2[(long)(n0 + nn) * 128 + (1 - half) * 64 + k0 + kb + j] = 0;
        }
        return;
    }

    if (b < 2912) {
        int l = b - 2656, bx = l & 7, by = l >> 3;
        int n0 = bx * 128, k0 = by * 32;
        int e = k0 >> 6, dd0 = k0 & 63;
        #pragma unroll
        for (int ll = 0; ll < 16; ++ll) {
            int idx = tid + ll * 256;
            int kk = idx >> 7, nn = idx & 127;
            t[kk][nn] = gw0[(long)((dd0 + kk) * 16 + e) * 1024 + n0 + nn];
        }
        __syncthreads();
        int nn = tid >> 1, kb = (tid & 1) * 16;
        #pragma unroll
        for (int j = 0; j < 16; ++j)
            W0p[(long)(n0 + nn) * 1024 + k0 + kb + j] = __float2bfloat16(t[kb + j][nn]);
        return;
    }

    {
        int by = b - 2912;
        int k0 = by * 32;
        #pragma unroll
        for (int ll = 0; ll < 16; ++ll) {
            int idx = tid + ll * 256;
            int kk = idx >> 7, nn = idx & 127;
            t[kk][nn] = l0w[(long)(k0 + kk) * 128 + nn];
        }
        __syncthreads();
        int nn = tid >> 1, kb = (tid & 1) * 16;
        #pragma unroll
        for (int j = 0; j < 16; ++j)
            l0wyt[(long)nn * 1024 + k0 + kb + j] = __float2bfloat16(t[kb + j][nn]);
        return;
    }
}

// ====== GEMM 3-SLOT v2: 128x128 tile, 3 blocks/CU, exact 2-round packing ===
// R7 diagnosis: 768 heavy 32-phase blocks on 512 slots = 1.5 rounds -> wall
// 64 phase-units vs ideal 52 (23% structural loss; occupancy avg 35.7<50).
// v2: halve the quantum. BM=BN=128, BK=32, 256 thr / 4 waves (2Mx2N,
// per-wave 64x64 = identical math/swizzle/ledger as R5, half-size regions).
// LDS 48 KB = 3 slots x (A 8 KB + B 8 KB) -> 3 blocks/CU = 768 slots.
// Heavy tiles: grp0 1024 + grp2 512 = 1536 = EXACTLY 2 rounds; grp1 1024
// light (nt=4) packs the tail. Stage = 4 gll16/wave -> VM4 ledger (lead-2,
// 3-slot rotation, proof identical to R5). Hot loop unrolled by slot period
// (3) with compile-time slots. K-order per output unchanged -> bit-identical.
// Aux tail blocks: [2560,2568) WgT reduce, 2568 biasfold, [2569,2586) W2
// swizzle preps (feed only tail_plus/tail_mfma; stream-ordered safe).
__global__ __launch_bounds__(256, 3) void gemm3s(
    const short* __restrict__ yb, const short* __restrict__ W1yt,
    __hip_bfloat16* __restrict__ Y1b,
    const short* __restrict__ Mt2, const short* __restrict__ W1m2,
    __hip_bfloat16* __restrict__ Mpb,
    const short* __restrict__ W0p, const float* __restrict__ gb0,
    __hip_bfloat16* __restrict__ H0b,
    const float* __restrict__ wgtp, __hip_bfloat16* __restrict__ WgTb,
    const float* __restrict__ l0w, const float* __restrict__ l0b,
    const float* __restrict__ gb1, const float* __restrict__ lW2,
    const float* __restrict__ l1w, float* __restrict__ bing,
    short* __restrict__ W2sb, short* __restrict__ L1ws,
    double* __restrict__ acc_g, int* __restrict__ counter)
{
    __shared__ __align__(16) char smem[49152];
    const int tid = threadIdx.x;
    const int lane = tid & 63, w = tid >> 6;
    const int l15 = lane & 15, l4 = lane >> 4;
    const int wr = w >> 1, wc = w & 1;

    const int bid = blockIdx.x;

    if (bid >= 2560) {
        if (bid < 2568) {
            // ---- WgT reduce: col-slab of 128; 8 f32 partials -> bf16 ----
            const int rb = bid - 2560;
            #pragma unroll
            for (int j = 0; j < 16; ++j) {
                int i4 = tid + j * 256;
                int flat = i4 * 4;
                int row = flat >> 7, cc = flat & 127;
                const long base = (long)row * 1024 + rb * 128 + cc;
                f32x4 s = {};
                #pragma unroll
                for (int ks = 0; ks < 8; ++ks) {
                    f32x4 v = *(const f32x4*)&wgtp[(long)ks * 131072 + base];
                    s += v;
                }
                union { ushort4 u; __hip_bfloat16 h[4]; } o;
                o.h[0] = __float2bfloat16(s[0]);
                o.h[1] = __float2bfloat16(s[1]);
                o.h[2] = __float2bfloat16(s[2]);
                o.h[3] = __float2bfloat16(s[3]);
                *(ushort4*)&WgTb[base] = o.u;
            }
            return;
        }
        if (bid == 2568) {
            // ---- biasfold (parallel, 2-way k-split) + acc/counter zero ----
            float* part = (float*)smem;
            const int c = tid & 127, h2 = tid >> 7;
            float s = h2 ? 0.f : l0b[c];
            const float* p = l0w + (long)(1024 + h2 * 512) * 128 + c;
            const float* g = gb1 + h2 * 512;
            #pragma unroll 8
            for (int o = 0; o < 512; ++o)
                s = fmaf(g[o], p[(long)o * 128], s);
            part[tid] = s;
            __syncthreads();
            if (tid < 128) bing[tid] = part[tid] + part[tid + 128];
            if (tid == 255) { acc_g[0] = 0.0; acc_g[1] = 0.0; *counter = 0; }
            return;
        }
        {
            // ---- W2 swizzle preps, two 64-col halves in [128][65] f32 ----
            int bb = bid - 2569;
            const float* in = (bb < 16) ? lW2 + (long)bb * 16384 : l1w;
            short* out = (bb < 16) ? W2sb + (long)bb * 16384 : L1ws;
            float (*t2)[65] = (float(*)[65])smem;
            #pragma unroll
            for (int h = 0; h < 2; ++h) {
                if (h) __syncthreads();
                #pragma unroll
                for (int l = 0; l < 32; ++l) {
                    int idx = l * 256 + tid;
                    int kk = idx >> 6, cc = idx & 63;
                    t2[kk][cc] = in[(long)kk * 128 + h * 64 + cc];
                }
                __syncthreads();
                #pragma unroll
                for (int l = 0; l < 4; ++l) {
                    int c2 = l * 256 + tid;
                    int col = h * 64 + (c2 >> 4), kc = c2 & 15;
                    int kcs = kc ^ (col & 7);
                    union { short8 v; short s[8]; } u;
                    #pragma unroll
                    for (int j = 0; j < 8; ++j)
                        u.s[j] = f2bf_s(t2[kc * 8 + j][col - h * 64]);
                    *(short8*)&out[col * 128 + kcs * 8] = u.v;
                }
            }
            return;
        }
    }

    const int xcd = bid & 7;
    const int idx = bid >> 3;

    int grp, bm, bn, K;
    const short* A; const short* Wt; __hip_bfloat16* C; int ldc;
    if (idx < 128) {
        grp = 0; const int c = idx >> 3, r = idx & 7;
        bm = (xcd * 8 + r) * 128; bn = c * 128;
        A = yb; Wt = W1yt + (long)bn * 1024; K = 1024; C = Y1b; ldc = 2048;
    } else if (idx < 192) {
        int j = idx - 128; const int c = j >> 3, r = j & 7;
        grp = 2; bm = (xcd * 8 + r) * 128; bn = c * 128;
        A = Mt2; Wt = W0p + (long)bn * 1024; K = 1024; C = H0b; ldc = 1024;
    } else {
        int j = idx - 192; const int c = j >> 3, r = j & 7;
        grp = 1; bm = (xcd * 8 + r) * 128; bn = c * 128;
        A = Mt2 + (long)(bn >> 8) * (8192L * 128);
        Wt = W1m2 + (long)bn * 128; K = 128; C = Mpb; ldc = 2048;
    }
    const int nt = K >> 5;

    auto STAGE = [&](int t, int sl) {
        char* base = smem + sl * 16384;
        #pragma unroll
        for (int p = 0; p < 2; ++p) {
            const int u = p * 256 + tid;
            const int row = u >> 2;
            const int sg = (tid & 3) ^ ((row >> 1) & 3);
            const short* asrc;
            if (grp == 2) {
                const int g = t * 4 + sg;
                asrc = A + (long)(g >> 4) * (8192L * 128)
                         + (long)(bm + row) * 128 + (g & 15) * 8;
            } else {
                asrc = A + (long)(bm + row) * K + t * 32 + sg * 8;
            }
            gll16(asrc, base + p * 4096 + w * 1024);
            gll16(Wt + (long)row * K + t * 32 + sg * 8,
                  base + 8192 + p * 4096 + w * 1024);
        }
    };

    f32x4 acc[4][4] = {};
    const int xr = (l4 ^ ((l15 >> 1) & 3)) * 16;
    const int aOff = (wr * 64 + l15) * 64 + xr;
    const int bOff = 8192 + (wc * 64 + l15) * 64 + xr;

    // mode 0: stage(tn -> sl2) + VM4   1: no stage, VM0   2: bare
    auto PHASE = [&](int sl, int tn, int sl2, int mode) {
        const char* base = smem + sl * 16384;
        short8 a_[4], b_[4];
        #pragma unroll
        for (int m = 0; m < 4; ++m)
            a_[m] = *(const short8*)(base + aOff + m * 1024);
        #pragma unroll
        for (int n = 0; n < 4; ++n)
            b_[n] = *(const short8*)(base + bOff + n * 1024);
        if (mode == 0) { STAGE(tn, sl2); VM4; }
        else if (mode == 1) { VM0; }
        FENCE(); BAR; FENCE();
        __builtin_amdgcn_s_setprio(1);
        #pragma unroll
        for (int m = 0; m < 4; ++m)
            #pragma unroll
            for (int n = 0; n < 4; ++n)
                acc[m][n] = __builtin_amdgcn_mfma_f32_16x16x32_bf16(
                    a_[m], b_[n], acc[m][n], 0, 0, 0);
        __builtin_amdgcn_s_setprio(0);
        FENCE(); BAR; FENCE();
    };

    // prologue: stage tiles 0,1 -> slots 0,1; VM4 retires tile 0
    STAGE(0, 0);
    STAGE(1, 1);
    VM4; FENCE(); BAR; FENCE();

    const int ntri = (nt - 2) / 3;       // 10 for nt=32, 0 for nt=4
    int t = 0;
    for (int i = 0; i < ntri; ++i, t += 3) {   // compile-time slots
        PHASE(0, t + 2, 2, 0);
        PHASE(1, t + 3, 0, 0);
        PHASE(2, t + 4, 1, 0);
    }
    int sl = t % 3;
    for (; t < nt - 2; ++t) {            // remainder (nt=4 path)
        const int sl2 = (sl == 0) ? 2 : sl - 1;
        PHASE(sl, t + 2, sl2, 0);
        sl = (sl == 2) ? 0 : sl + 1;
    }
    PHASE(sl, 0, 0, 1);                  // tile nt-2, drain to VM0
    sl = (sl == 2) ? 0 : sl + 1;
    PHASE(sl, 0, 0, 2);                  // tile nt-1, bare

    #pragma unroll
    for (int m = 0; m < 4; ++m) {
        const int row = bm + wr * 64 + m * 16 + l4 * 4;
        #pragma unroll
        for (int n = 0; n < 4; ++n) {
            const int col = bn + wc * 64 + n * 16 + l15;
            const float bv = (grp == 2) ? gb0[col] : 0.f;
            #pragma unroll
            for (int r = 0; r < 4; ++r) {
                float v = acc[m][n][r] + bv;
                if (grp == 2) v = fmaxf(v, 0.f);
                C[(long)(row + r) * ldc + col] = __float2bfloat16(v);
            }
        }
    }
}

// ===== tail_plus v2: W2 read direct from L2 (no LDS stage) -> 34.5 KB LDS,
// 4 blocks/CU. [0,2048) local tail, [2048,2112) Tg, [2112,2176) Ty =========
__global__ __launch_bounds__(256) void tail_plus(
    const __hip_bfloat16* __restrict__ Yp, const __hip_bfloat16* __restrict__ Mq,
    const float* __restrict__ bin, const short* __restrict__ W2s,
    const float* __restrict__ b2, const float* __restrict__ w3,
    const float* __restrict__ b3, double* __restrict__ acc,
    const short* __restrict__ H0b, const short* __restrict__ WgTb,
    __hip_bfloat16* __restrict__ Tgb,
    const short* __restrict__ ybs, const short* __restrict__ l0ws,
    __hip_bfloat16* __restrict__ Tyb)
{
    __shared__ __align__(16) char smem[35328];
    const int bid = blockIdx.x;
    const int tid = threadIdx.x;
    const int lane = tid & 63;
    const int l15 = lane & 15, l4 = lane >> 4;

    if (bid >= 2048) {
        const int sel = bid - 2048;
        const short* Ain = (sel < 64) ? H0b : ybs;
        const short* Bin = (sel < 64) ? WgTb : l0ws;
        __hip_bfloat16* Co = (sel < 64) ? Tgb : Tyb;
        short* As = (short*)smem;
        short* Bs = (short*)(smem + 16384);
        const int w = tid >> 6;
        const int wr = w >> 1, wc = w & 1;
        const int bm = (sel & 63) * 128;
        const int srow = lane >> 3;
        const int gsrc = (lane & 7) ^ srow;

        f32x4 a4[4][4] = {};
        for (int k0 = 0; k0 < 1024; k0 += 64) {
            #pragma unroll
            for (int s = 0; s < 4; ++s) {
                const int rrel = s * 32 + w * 8 + srow;
                gll16(Ain + (long)(bm + rrel) * 1024 + k0 + gsrc * 8,
                      As + (s * 32 + w * 8) * 64);
                gll16(Bin + (long)rrel * 1024 + k0 + gsrc * 8,
                      Bs + (s * 32 + w * 8) * 64);
            }
            __syncthreads();
            #pragma unroll
            for (int st = 0; st < 2; ++st) {
                const int gr = (st * 4 + l4) ^ (l15 & 7);
                short8 a[4], b[4];
                #pragma unroll
                for (int m = 0; m < 4; ++m)
                    a[m] = *(const short8*)&As[(wr * 64 + m * 16 + l15) * 64 + gr * 8];
                #pragma unroll
                for (int n = 0; n < 4; ++n)
                    b[n] = *(const short8*)&Bs[(wc * 64 + n * 16 + l15) * 64 + gr * 8];
                #pragma unroll
                for (int m = 0; m < 4; ++m)
                    #pragma unroll
                    for (int n = 0; n < 4; ++n)
                        a4[m][n] = __builtin_amdgcn_mfma_f32_16x16x32_bf16(a[m], b[n], a4[m][n], 0, 0, 0);
            }
            __syncthreads();
        }
        #pragma unroll
        for (int m = 0; m < 4; ++m) {
            int row = bm + (w >> 1) * 64 + m * 16 + l4 * 4;
            #pragma unroll
            for (int n = 0; n < 4; ++n) {
                int col = (w & 1) * 64 + n * 16 + l15;
                #pragma unroll
                for (int r = 0; r < 4; ++r)
                    Co[(long)(row + r) * 128 + col] = __float2bfloat16(a4[m][n][r]);
            }
        }
        return;
    }

    const int wkid = (bid & 7) * 256 + (bid >> 3);
    const int e = wkid & 15;
    const int b0 = (wkid >> 4) * 64;
    const int cbase = e * 128;
    const int wid = tid >> 6;
    const int side = wid >> 1;
    const int wr = wid & 1;
    const int widthIn = 2048;

    short* h1 = (short*)smem;                  // 32 KB
    float* bins = (float*)(smem + 32768);
    float* b2s  = (float*)(smem + 33280);
    float* w3s  = (float*)(smem + 33792);
    float* red  = (float*)(smem + 34304);

    const short* W2e = W2s + (long)e * 16384;  // L2-resident, read direct
    if (tid < 128) {
        bins[tid] = bin[cbase + tid];
        b2s[tid]  = b2[cbase + tid];
        w3s[tid]  = w3[cbase + tid];
    }
    __syncthreads();

    const short* Ys = (const short*)Yp;
    const short* Ms = (const short*)Mq;
    #pragma unroll
    for (int c = 0; c < 4; ++c) {
        int chunk = c * 256 + tid;
        int row = chunk >> 4, kc = chunk & 15;
        short8 yv = *(const short8*)&Ys[(long)(b0 + row) * widthIn + cbase + kc * 8];
        float yf[8];
        #pragma unroll
        for (int j = 0; j < 8; ++j) yf[j] = bf2f(yv[j]) + bins[kc * 8 + j];
        int dst = row * 128 + (kc ^ (row & 7)) * 8;
        #pragma unroll
        for (int s = 0; s < 2; ++s) {
            int rowm = (b0 + row + s) & (B_ROWS - 1);
            short8 mv = *(const short8*)&Ms[(long)rowm * widthIn + cbase + kc * 8];
            union { short8 v; short sh[8]; } o;
            #pragma unroll
            for (int j = 0; j < 8; ++j)
                o.sh[j] = f2bf_s(fmaxf(yf[j] + bf2f(mv[j]), 0.f));
            *(short8*)&h1[s * 8192 + dst] = o.v;
        }
    }
    __syncthreads();

    f32x4 accv[2][8] = {};
    #pragma unroll
    for (int st = 0; st < 4; ++st) {
        short8 a[2], b[8];
        #pragma unroll
        for (int m = 0; m < 2; ++m) {
            int row = wr * 32 + m * 16 + l15;
            int ch = (st * 4 + l4) ^ (row & 7);
            a[m] = *(const short8*)&h1[side * 8192 + row * 128 + ch * 8];
        }
        #pragma unroll
        for (int n = 0; n < 8; ++n) {
            int col = n * 16 + l15;
            int ch = (st * 4 + l4) ^ (col & 7);
            b[n] = *(const short8*)&W2e[col * 128 + ch * 8];
        }
        #pragma unroll
        for (int m = 0; m < 2; ++m)
            #pragma unroll
            for (int n = 0; n < 8; ++n)
                accv[m][n] = __builtin_amdgcn_mfma_f32_16x16x32_bf16(a[m], b[n], accv[m][n], 0, 0, 0);
    }

    float p[2][4] = {};
    #pragma unroll
    for (int m = 0; m < 2; ++m)
        #pragma unroll
        for (int n = 0; n < 8; ++n) {
            int colL = n * 16 + l15;
            float bb = b2s[colL], ww = w3s[colL];
            #pragma unroll
            for (int r = 0; r < 4; ++r) {
                float h2 = fmaxf(accv[m][n][r] + bb, 0.f);
                p[m][r] = fmaf(h2, ww, p[m][r]);
            }
        }
    #pragma unroll
    for (int m = 0; m < 2; ++m)
        #pragma unroll
        for (int r = 0; r < 4; ++r)
            #pragma unroll
            for (int off = 1; off < 16; off <<= 1)
                p[m][r] += __shfl_xor(p[m][r], off, 64);

    float mysum = 0.f;
    if (l15 == 0) {
        float bb = b3[e];
        #pragma unroll
        for (int m = 0; m < 2; ++m)
            #pragma unroll
            for (int r = 0; r < 4; ++r) {
                float s = p[m][r] + bb;
                mysum += softplus_f(side ? s : -s);
            }
    }
    red[tid] = mysum;
    __syncthreads();
    for (int s2 = 128; s2 > 0; s2 >>= 1) {
        if (tid < s2) red[tid] += red[tid + s2];
        __syncthreads();
    }
    if (tid == 0) atomicAdd(acc, (double)red[0]);
}

// ---------- global tail + fused finalize (last-block pattern) --------------
__global__ __launch_bounds__(256) void tail_mfma(
    const __hip_bfloat16* __restrict__ Yp, const __hip_bfloat16* __restrict__ Mq,
    const float* __restrict__ bin,
    const short* __restrict__ W2s,
    const float* __restrict__ b2, const float* __restrict__ w3,
    const float* __restrict__ b3,
    int widthIn, double* __restrict__ acc, int* __restrict__ counter,
    float* __restrict__ out)
{
    const int b0 = blockIdx.x * 64;
    const int e = blockIdx.y;
    const int cbase = e * 128;
    const int tid = threadIdx.x;
    const int lane = tid & 63;
    const int wid = tid >> 6;
    const int side = wid >> 1;
    const int wr = wid & 1;

    __shared__ __align__(16) short h1[2 * 64 * 128];
    __shared__ __align__(16) short Bs[128 * 128];
    __shared__ float bins[128], b2s[128], w3s[128];
    __shared__ float red[256];

    const short* W2e = W2s + (long)e * 16384;
    #pragma unroll
    for (int l = 0; l < 8; ++l) {
        int cb = (l * 4 + wid) * 64;
        gll16(W2e + (long)(cb + lane) * 8, &Bs[cb * 8]);
    }
    if (tid < 128) {
        bins[tid] = bin[cbase + tid];
        b2s[tid]  = b2[cbase + tid];
        w3s[tid]  = w3[cbase + tid];
    }
    __syncthreads();

    const short* Ys = (const short*)Yp;
    const short* Ms = (const short*)Mq;
    #pragma unroll
    for (int c = 0; c < 4; ++c) {
        int chunk = c * 256 + tid;
        int row = chunk >> 4, kc = chunk & 15;
        short8 yv = *(const short8*)&Ys[(long)(b0 + row) * widthIn + cbase + kc * 8];
        float yf[8];
        #pragma unroll
        for (int j = 0; j < 8; ++j) yf[j] = bf2f(yv[j]) + bins[kc * 8 + j];
        int dst = row * 128 + (kc ^ (row & 7)) * 8;
        #pragma unroll
        for (int s = 0; s < 2; ++s) {
            int rowm = (b0 + row + s) & (B_ROWS - 1);
            short8 mv = *(const short8*)&Ms[(long)rowm * widthIn + cbase + kc * 8];
            union { short8 v; short sh[8]; } o;
            #pragma unroll
            for (int j = 0; j < 8; ++j)
                o.sh[j] = f2bf_s(fmaxf(yf[j] + bf2f(mv[j]), 0.f));
            *(short8*)&h1[s * 8192 + dst] = o.v;
        }
    }
    __syncthreads();

    const int l15 = lane & 15, l4 = lane >> 4;
    f32x4 accv[2][8] = {};
    #pragma unroll
    for (int st = 0; st < 4; ++st) {
        short8 a[2], b[8];
        #pragma unroll
        for (int m = 0; m < 2; ++m) {
            int row = wr * 32 + m * 16 + l15;
            int ch = (st * 4 + l4) ^ (row & 7);
            a[m] = *(const short8*)&h1[side * 8192 + row * 128 + ch * 8];
        }
        #pragma unroll
        for (int n = 0; n < 8; ++n) {
            int col = n * 16 + l15;
            int ch = (st * 4 + l4) ^ (col & 7);
            b[n] = *(const short8*)&Bs[col * 128 + ch * 8];
        }
        #pragma unroll
        for (int m = 0; m < 2; ++m)
            #pragma unroll
            for (int n = 0; n < 8; ++n)
                accv[m][n] = __builtin_amdgcn_mfma_f32_16x16x32_bf16(a[m], b[n], accv[m][n], 0, 0, 0);
    }

    float p[2][4] = {};
    #pragma unroll
    for (int m = 0; m < 2; ++m)
        #pragma unroll
        for (int n = 0; n < 8; ++n) {
            int colL = n * 16 + l15;
            float bb = b2s[colL], ww = w3s[colL];
            #pragma unroll
            for (int r = 0; r < 4; ++r) {
                float h2 = fmaxf(accv[m][n][r] + bb, 0.f);
                p[m][r] = fmaf(h2, ww, p[m][r]);
            }
        }
    #pragma unroll
    for (int m = 0; m < 2; ++m)
        #pragma unroll
        for (int r = 0; r < 4; ++r)
            #pragma unroll
            for (int off = 1; off < 16; off <<= 1)
                p[m][r] += __shfl_xor(p[m][r], off, 64);

    float mysum = 0.f;
    if (l15 == 0) {
        float bb = b3[e];
        #pragma unroll
        for (int m = 0; m < 2; ++m)
            #pragma unroll
            for (int r = 0; r < 4; ++r) {
                float s = p[m][r] + bb;
                mysum += softplus_f(side ? s : -s);
            }
    }
    red[tid] = mysum;
    __syncthreads();
    for (int s2 = 128; s2 > 0; s2 >>= 1) {
        if (tid < s2) red[tid] += red[tid + s2];
        __syncthreads();
    }
    if (tid == 0) {
        atomicAdd(acc + 1, (double)red[0]);
        __threadfence();
        int old = atomicAdd(counter, 1);
        if (old == (int)(gridDim.x * gridDim.y) - 1) {
            double a0 = atomicAdd(acc + 0, 0.0);
            double a1 = atomicAdd(acc + 1, 0.0);
            out[0] = (float)(a0 / (8192.0 * 16.0) + 0.5 * a1 / 8192.0);
        }
    }
}

extern "C" void kernel_launch(void* const* d_in, const int* in_sizes, int n_in,
                              void* d_out, int out_size, void* d_ws, size_t ws_size,
                              hipStream_t stream)
{
    const float* y   = (const float*)d_in[0];
    const float* M   = (const float*)d_in[1];
    const float* gw0 = (const float*)d_in[2];
    const float* gb0 = (const float*)d_in[3];
    const float* gw1 = (const float*)d_in[4];
    const float* gb1 = (const float*)d_in[5];
    const float* l0w = (const float*)d_in[6];
    const float* l0b = (const float*)d_in[7];
    const float* l1w = (const float*)d_in[8];
    const float* l1b = (const float*)d_in[9];
    const float* l2w = (const float*)d_in[10];
    const float* l2b = (const float*)d_in[11];
    const float* lW1 = (const float*)d_in[12];
    const float* lb1 = (const float*)d_in[13];
    const float* lW2 = (const float*)d_in[14];
    const float* lb2 = (const float*)d_in[15];
    const float* lW3 = (const float*)d_in[16];
    const float* lb3 = (const float*)d_in[17];

    // ---- workspace layout (~127 MB) ----
    char* w = (char*)d_ws;
    double* acc = (double*)w;
    int* counter = (int*)(w + 16);
    float* bing = (float*)(w + 256);
    const size_t MB = 1u << 20;
    __hip_bfloat16* Y1b  = (__hip_bfloat16*)(w + 4096);             // 32 MB
    __hip_bfloat16* Mpb  = (__hip_bfloat16*)(w + 4096 + 32 * MB);   // 32 MB
    __hip_bfloat16* H0b  = (__hip_bfloat16*)(w + 4096 + 64 * MB);   // 16 MB
    short*          Mt2  = (short*)(w + 4096 + 80 * MB);            // 16 MB
    __hip_bfloat16* yb   = (__hip_bfloat16*)(w + 4096 + 96 * MB);   // 16 MB
    __hip_bfloat16* W1yt = (__hip_bfloat16*)(w + 4096 + 112 * MB);  // 4 MB
    __hip_bfloat16* W0p  = (__hip_bfloat16*)(w + 4096 + 118 * MB);  // 2 MB
    __hip_bfloat16* l0wyt = (__hip_bfloat16*)(w + 4096 + 120 * MB); // 256 KB
    short* W2sb = (short*)(w + 4096 + 120 * MB + 512 * 1024);       // 512 KB
    short* L1ws = (short*)(w + 4096 + 121 * MB);                    // 32 KB
    __hip_bfloat16* WgTb = (__hip_bfloat16*)(w + 4096 + 121 * MB + 512 * 1024); // 256 KB
    short* W1m2 = (short*)(w + 4096 + 122 * MB);                    // 512 KB
    __hip_bfloat16* Tyb = (__hip_bfloat16*)(w + 4096 + 123 * MB);   // 2 MB
    __hip_bfloat16* Tgb = (__hip_bfloat16*)(w + 4096 + 125 * MB);   // 2 MB
    // WgT split-K f32 partials: 4 MB scratch overlaying Tyb+Tgb (free until
    // tail_plus; consumed by gemm3s reduce blocks -> WgTb, stream-ordered)
    float* wgtp = (float*)(w + 4096 + 123 * MB);

    dim3 blk(256);

    prep_all<<<dim3(2944), blk, 0, stream>>>(
        y, M, lW1, gw0, l0w, gw1,
        yb, Mt2, W1yt, W1m2, W0p, l0wyt, wgtp);

    gemm3s<<<dim3(2586), blk, 0, stream>>>(
        (const short*)yb, (const short*)W1yt, Y1b,
        Mt2, W1m2, Mpb,
        (const short*)W0p, gb0, H0b,
        wgtp, WgTb,
        l0w, l0b, gb1, lW2, l1w, bing, W2sb, L1ws,
        acc, counter);

    tail_plus<<<dim3(2176), blk, 0, stream>>>(
        Y1b, Mpb, lb1, W2sb, lb2, lW3, lb3, acc,
        (const short*)H0b, (const short*)WgTb, Tgb,
        (const short*)yb, (const short*)l0wyt, Tyb);

    tail_mfma<<<dim3(128, 1), blk, 0, stream>>>(
        Tyb, Tgb, bing, L1ws, l1b, l2w, l2b, 128, acc, counter,
        (float*)d_out);
}

// Round 9
// 170.160 us; speedup vs baseline: 1.0915x; 1.0915x over previous
//
#include <hip/hip_runtime.h>
#include <hip/hip_bf16.h>
#include <math.h>

#define B_ROWS 8192
#define NEXP 16

typedef __attribute__((ext_vector_type(8))) short short8;
typedef __attribute__((ext_vector_type(4))) float f32x4;

__device__ __forceinline__ float softplus_f(float x) {
    return fmaxf(x, 0.f) + log1pf(expf(-fabsf(x)));
}

__device__ __forceinline__ float bf2f(short u) {
    union { unsigned int i; float f; } c;
    c.i = ((unsigned int)(unsigned short)u) << 16;
    return c.f;
}

__device__ __forceinline__ short f2bf_s(float x) {
    __hip_bfloat16 h = __float2bfloat16(x);
    return *(short*)&h;
}

__device__ __forceinline__ void gll16(const void* g, void* l) {
    __builtin_amdgcn_global_load_lds(
        (const __attribute__((address_space(1))) void*)g,
        (__attribute__((address_space(3))) void*)l, 16, 0, 0);
}

#define FENCE() asm volatile("" ::: "memory")
#define VM3 asm volatile("s_waitcnt vmcnt(3)" ::: "memory")
#define VM0 asm volatile("s_waitcnt vmcnt(0)" ::: "memory")
#define BAR __builtin_amdgcn_s_barrier()

// ================= UBER PREP v4 (unchanged from R8) ========================
// [0,64)        WgT split-K partials (ct = b&7, ks = b>>3)
// [64,1088)     y cast (8 float4/thread)
// [1088,2112)   Mt2 permute
// [2112,2624)   W1yt tcast
// [2624,2656)   W1m2 zero-padded tcast
// [2656,2912)   W0p prep
// [2912,2944)   l0wyt tcast
__global__ __launch_bounds__(256) void prep_all(
    const float* __restrict__ y, const float* __restrict__ M,
    const float* __restrict__ lW1, const float* __restrict__ gw0,
    const float* __restrict__ l0w, const float* __restrict__ gw1,
    __hip_bfloat16* __restrict__ yb, short* __restrict__ Mt2,
    __hip_bfloat16* __restrict__ W1yt, short* __restrict__ W1m2,
    __hip_bfloat16* __restrict__ W0p, __hip_bfloat16* __restrict__ l0wyt,
    float* __restrict__ wgtp)
{
    __shared__ __align__(16) char smem[33280];
    const int b = blockIdx.x;
    const int tid = threadIdx.x;
    const int lane = tid & 63, w = tid >> 6;

    if (b < 64) {
        short* As = (short*)smem;
        short* Bs = (short*)(smem + 16384);
        const int ct = b & 7, ks = b >> 3;
        const int bn = ct * 128;
        const int wr = w >> 1, wc = w & 1;
        const int l15 = lane & 15, l4 = lane >> 4;

        f32x4 acc4[4][4] = {};
        for (int kq = 0; kq < 2; ++kq) {
            const int k0 = ks * 128 + kq * 64;
            {
                int c4 = (tid & 31) * 4;
                int kkr0 = tid >> 5;
                #pragma unroll
                for (int r = 0; r < 8; ++r) {
                    int kk = r * 8 + kkr0;
                    float4 v = *(const float4*)&l0w[(long)(1024 + k0 + kk) * 128 + c4];
                    int g = kk >> 3, sub = kk & 7;
                    #pragma unroll
                    for (int i = 0; i < 4; ++i) {
                        int row = c4 + i;
                        As[row * 64 + (g ^ (row & 7)) * 8 + sub] = f2bf_s(((const float*)&v)[i]);
                    }
                }
            }
            {
                int jr0 = tid >> 3;
                int g = tid & 7;
                #pragma unroll
                for (int s = 0; s < 4; ++s) {
                    int jrel = s * 32 + jr0;
                    const float* src = &gw1[(long)(bn + jrel) * 1024 + k0 + g * 8];
                    float4 v0 = *(const float4*)src;
                    float4 v1 = *(const float4*)(src + 4);
                    union { short8 v; short sh[8]; } o;
                    o.sh[0] = f2bf_s(v0.x); o.sh[1] = f2bf_s(v0.y);
                    o.sh[2] = f2bf_s(v0.z); o.sh[3] = f2bf_s(v0.w);
                    o.sh[4] = f2bf_s(v1.x); o.sh[5] = f2bf_s(v1.y);
                    o.sh[6] = f2bf_s(v1.z); o.sh[7] = f2bf_s(v1.w);
                    *(short8*)&Bs[jrel * 64 + (g ^ (jrel & 7)) * 8] = o.v;
                }
            }
            __syncthreads();
            #pragma unroll
            for (int st = 0; st < 2; ++st) {
                const int gr = (st * 4 + l4) ^ (l15 & 7);
                short8 a[4], bv[4];
                #pragma unroll
                for (int m = 0; m < 4; ++m)
                    a[m] = *(const short8*)&As[(wr * 64 + m * 16 + l15) * 64 + gr * 8];
                #pragma unroll
                for (int n = 0; n < 4; ++n)
                    bv[n] = *(const short8*)&Bs[(wc * 64 + n * 16 + l15) * 64 + gr * 8];
                #pragma unroll
                for (int m = 0; m < 4; ++m)
                    #pragma unroll
                    for (int n = 0; n < 4; ++n)
                        acc4[m][n] = __builtin_amdgcn_mfma_f32_16x16x32_bf16(a[m], bv[n], acc4[m][n], 0, 0, 0);
            }
            __syncthreads();
        }
        #pragma unroll
        for (int m = 0; m < 4; ++m) {
            int row = wr * 64 + m * 16 + l4 * 4;
            #pragma unroll
            for (int n = 0; n < 4; ++n) {
                int col = bn + wc * 64 + n * 16 + l15;
                #pragma unroll
                for (int r = 0; r < 4; ++r)
                    wgtp[((long)ks * 128 + row + r) * 1024 + col] = acc4[m][n][r];
            }
        }
        return;
    }

    if (b < 1088) {
        const long base = (long)(b - 64) * 2048;
        #pragma unroll
        for (int j = 0; j < 8; ++j) {
            long i = base + j * 256 + tid;
            float4 v = ((const float4*)y)[i];
            union { ushort4 u; __hip_bfloat16 h[4]; } p;
            p.h[0] = __float2bfloat16(v.x);
            p.h[1] = __float2bfloat16(v.y);
            p.h[2] = __float2bfloat16(v.z);
            p.h[3] = __float2bfloat16(v.w);
            ((ushort4*)yb)[i] = p.u;
        }
        return;
    }

    if (b < 2112) {
        short* t = (short*)smem;
        const long r0 = (long)(b - 1088) * 8;
        #pragma unroll
        for (int i = 0; i < 8; ++i) {
            int idx = i * 1024 + tid * 4;
            float4 v = *(const float4*)&M[r0 * 1024 + idx];
            short4 s;
            s.x = f2bf_s(v.x); s.y = f2bf_s(v.y); s.z = f2bf_s(v.z); s.w = f2bf_s(v.w);
            *(short4*)&t[idx] = s;
        }
        __syncthreads();
        const int e = tid & 15, rr = (tid >> 4) & 7, hf = tid >> 7;
        #pragma unroll
        for (int c = 0; c < 4; ++c) {
            union { short8 v; short s[8]; } o;
            #pragma unroll
            for (int j = 0; j < 8; ++j)
                o.s[j] = t[rr * 1024 + (hf * 32 + c * 8 + j) * 16 + e];
            *(short8*)&Mt2[(long)(e >> 1) * (8192L * 128) + (r0 + rr) * 128
                           + (e & 1) * 64 + hf * 32 + c * 8] = o.v;
        }
        return;
    }

    float (*t)[129] = (float(*)[129])smem;

    if (b < 2624) {
        int l = b - 2112, bx = l & 15, by = l >> 4;
        int n0 = bx * 128, k0 = by * 32;
        long base = 64L * 128 + (long)bx * (1088L * 128);
        #pragma unroll
        for (int ll = 0; ll < 16; ++ll) {
            int idx = tid + ll * 256;
            int kk = idx >> 7, nn = idx & 127;
            t[kk][nn] = lW1[base + (long)(k0 + kk) * 128 + nn];
        }
        __syncthreads();
        int nn = tid >> 1, kb = (tid & 1) * 16;
        #pragma unroll
        for (int j = 0; j < 16; ++j)
            W1yt[(long)(n0 + nn) * 1024 + k0 + kb + j] = __float2bfloat16(t[kb + j][nn]);
        return;
    }

    if (b < 2656) {
        int l = b - 2624, bx = l & 15, by = l >> 4;
        int n0 = bx * 128, k0 = by * 32;
        long base = (long)bx * (1088L * 128);
        #pragma unroll
        for (int ll = 0; ll < 16; ++ll) {
            int idx = tid + ll * 256;
            int kk = idx >> 7, nn = idx & 127;
            if (kk < 32) t[kk][nn] = lW1[base + (long)(k0 + kk) * 128 + nn];
        }
        __syncthreads();
        int nn = tid >> 1, kb = (tid & 1) * 16;
        int half = bx & 1;
        #pragma unroll
        for (int j = 0; j < 16; ++j) {
            W1m2[(long)(n0 + nn) * 128 + half * 64 + k0 + kb + j] = f2bf_s(t[kb + j][nn]);
            W1m2[(long)(n0 + nn) * 128 + (1 - half) * 64 + k0 + kb + j] = 0;
        }
        return;
    }

    if (b < 2912) {
        int l = b - 2656, bx = l & 7, by = l >> 3;
        int n0 = bx * 128, k0 = by * 32;
        int e = k0 >> 6, dd0 = k0 & 63;
        #pragma unroll
        for (int ll = 0; ll < 16; ++ll) {
            int idx = tid + ll * 256;
            int kk = idx >> 7, nn = idx & 127;
            t[kk][nn] = gw0[(long)((dd0 + kk) * 16 + e) * 1024 + n0 + nn];
        }
        __syncthreads();
        int nn = tid >> 1, kb = (tid & 1) * 16;
        #pragma unroll
        for (int j = 0; j < 16; ++j)
            W0p[(long)(n0 + nn) * 1024 + k0 + kb + j] = __float2bfloat16(t[kb + j][nn]);
        return;
    }

    {
        int by = b - 2912;
        int k0 = by * 32;
        #pragma unroll
        for (int ll = 0; ll < 16; ++ll) {
            int idx = tid + ll * 256;
            int kk = idx >> 7, nn = idx & 127;
            t[kk][nn] = l0w[(long)(k0 + kk) * 128 + nn];
        }
        __syncthreads();
        int nn = tid >> 1, kb = (tid & 1) * 16;
        #pragma unroll
        for (int j = 0; j < 16; ++j)
            l0wyt[(long)nn * 1024 + k0 + kb + j] = __float2bfloat16(t[kb + j][nn]);
        return;
    }
}

// ========== GEMM 3-SLOT (R7 core, verbatim) + aux tail blocks ==============
// Core [0,1280): BM=128, BN=256, BK=32, 512 thr / 8 waves (2Mx4N), per-wave
// 64x64, LDS 72 KB = 3 slots x (A 8 KB + B 16 KB), 2 blocks/CU, VM3 counted
// ledger, slot = g^((row>>1)&3) swizzle. Proven 72 us / occ 35.7 / FETCH 46MB.
// Aux (512-thr adapted): [1280,1288) WgT reduce, 1288 biasfold (4-way
// k-split), [1289,1306) W2 swizzle preps. All feed only tail_plus/tail_mfma
// (stream-ordered safe).
__global__ __launch_bounds__(512, 4) void gemm3s(
    const short* __restrict__ yb, const short* __restrict__ W1yt,
    __hip_bfloat16* __restrict__ Y1b,
    const short* __restrict__ Mt2, const short* __restrict__ W1m2,
    __hip_bfloat16* __restrict__ Mpb,
    const short* __restrict__ W0p, const float* __restrict__ gb0,
    __hip_bfloat16* __restrict__ H0b,
    const float* __restrict__ wgtp, __hip_bfloat16* __restrict__ WgTb,
    const float* __restrict__ l0w, const float* __restrict__ l0b,
    const float* __restrict__ gb1, const float* __restrict__ lW2,
    const float* __restrict__ l1w, float* __restrict__ bing,
    short* __restrict__ W2sb, short* __restrict__ L1ws,
    double* __restrict__ acc_g, int* __restrict__ counter)
{
    __shared__ __align__(16) char smem[73728];
    const int tid = threadIdx.x;
    const int lane = tid & 63, w = tid >> 6;
    const int l15 = lane & 15, l4 = lane >> 4;
    const int wr = w >> 2, wc = w & 3;

    const int bid = blockIdx.x;

    if (bid >= 1280) {
        if (bid < 1288) {
            // ---- WgT reduce: col-slab of 128; 8 f32 partials -> bf16 ----
            const int rb = bid - 1280;
            #pragma unroll
            for (int j = 0; j < 8; ++j) {
                int i4 = tid + j * 512;            // float4 index in [0,4096)
                int flat = i4 * 4;
                int row = flat >> 7, cc = flat & 127;
                const long base = (long)row * 1024 + rb * 128 + cc;
                f32x4 s = {};
                #pragma unroll
                for (int ks = 0; ks < 8; ++ks) {
                    f32x4 v = *(const f32x4*)&wgtp[(long)ks * 131072 + base];
                    s += v;
                }
                union { ushort4 u; __hip_bfloat16 h[4]; } o;
                o.h[0] = __float2bfloat16(s[0]);
                o.h[1] = __float2bfloat16(s[1]);
                o.h[2] = __float2bfloat16(s[2]);
                o.h[3] = __float2bfloat16(s[3]);
                *(ushort4*)&WgTb[base] = o.u;
            }
            return;
        }
        if (bid == 1288) {
            // ---- biasfold: 4-way k-split over 512 thr + LDS combine ----
            float* part = (float*)smem;
            const int c = tid & 127, q = tid >> 7;      // q in 0..3
            float s = (q == 0) ? l0b[c] : 0.f;
            const float* p = l0w + (long)(1024 + q * 256) * 128 + c;
            const float* g = gb1 + q * 256;
            #pragma unroll 8
            for (int o = 0; o < 256; ++o)
                s = fmaf(g[o], p[(long)o * 128], s);
            part[tid] = s;
            __syncthreads();
            if (tid < 128)
                bing[tid] = part[tid] + part[tid + 128]
                          + part[tid + 256] + part[tid + 384];
            if (tid == 511) { acc_g[0] = 0.0; acc_g[1] = 0.0; *counter = 0; }
            return;
        }
        {
            // ---- W2 swizzle preps, two 64-col halves in [128][65] f32 ----
            int bb = bid - 1289;
            const float* in = (bb < 16) ? lW2 + (long)bb * 16384 : l1w;
            short* out = (bb < 16) ? W2sb + (long)bb * 16384 : L1ws;
            float (*t2)[65] = (float(*)[65])smem;
            #pragma unroll
            for (int h = 0; h < 2; ++h) {
                if (h) __syncthreads();
                #pragma unroll
                for (int l = 0; l < 16; ++l) {
                    int idx = l * 512 + tid;
                    int kk = idx >> 6, cc = idx & 63;
                    t2[kk][cc] = in[(long)kk * 128 + h * 64 + cc];
                }
                __syncthreads();
                #pragma unroll
                for (int l = 0; l < 2; ++l) {
                    int c2 = l * 512 + tid;
                    int col = h * 64 + (c2 >> 4), kc = c2 & 15;
                    int kcs = kc ^ (col & 7);
                    union { short8 v; short s[8]; } u;
                    #pragma unroll
                    for (int j = 0; j < 8; ++j)
                        u.s[j] = f2bf_s(t2[kc * 8 + j][col - h * 64]);
                    *(short8*)&out[col * 128 + kcs * 8] = u.v;
                }
            }
            return;
        }
    }

    const int xcd = bid & 7;
    const int idx = bid >> 3;

    int grp, bm, bn, K;
    const short* A; const short* Wt; __hip_bfloat16* C; int ldc;
    if (idx < 64) {
        grp = 0; const int c = idx >> 3, r = idx & 7;
        bm = (xcd * 8 + r) * 128; bn = c * 256;
        A = yb; Wt = W1yt + (long)bn * 1024; K = 1024; C = Y1b; ldc = 2048;
    } else if (idx < 96) {
        int j = idx - 64; const int c = j >> 3, r = j & 7;
        grp = 2; bm = (xcd * 8 + r) * 128; bn = c * 256;
        A = Mt2; Wt = W0p + (long)bn * 1024; K = 1024; C = H0b; ldc = 1024;
    } else {
        int j = idx - 96; const int c = j >> 3, r = j & 7;
        grp = 1; bm = (xcd * 8 + r) * 128; bn = c * 256;
        A = Mt2 + (long)(bn >> 8) * (8192L * 128);
        Wt = W1m2 + (long)bn * 128; K = 128; C = Mpb; ldc = 2048;
    }
    const int nt = K >> 5;

    const int rowA = tid >> 2;
    const int sgA  = (tid & 3) ^ ((rowA >> 1) & 3);
    const int rowB0 = tid >> 2;
    const int sgB0  = (tid & 3) ^ ((rowB0 >> 1) & 3);
    const int rowB1 = (tid + 512) >> 2;
    const int sgB1  = (tid & 3) ^ ((rowB1 >> 1) & 3);

    auto STAGE = [&](int t, int sl) {
        char* base = smem + sl * 24576;
        const short* asrc;
        if (grp == 2) {
            const int g = t * 4 + sgA;
            asrc = A + (long)(g >> 4) * (8192L * 128)
                     + (long)(bm + rowA) * 128 + (g & 15) * 8;
        } else {
            asrc = A + (long)(bm + rowA) * K + t * 32 + sgA * 8;
        }
        gll16(asrc, base + w * 1024);
        gll16(Wt + (long)rowB0 * K + t * 32 + sgB0 * 8,
              base + 8192 + w * 1024);
        gll16(Wt + (long)rowB1 * K + t * 32 + sgB1 * 8,
              base + 16384 + w * 1024);
    };

    f32x4 acc[4][4] = {};
    const int xr = (l4 ^ ((l15 >> 1) & 3)) * 16;
    const int aOff = (wr * 64 + l15) * 64 + xr;
    const int bOff = 8192 + (wc * 64 + l15) * 64 + xr;

    // mode 0: stage(tn)+VM3   1: no stage, VM0   2: bare
    auto PHASE = [&](int sl, int tn, int sl2, int mode) {
        const char* base = smem + sl * 24576;
        short8 a_[4], b_[4];
        #pragma unroll
        for (int m = 0; m < 4; ++m)
            a_[m] = *(const short8*)(base + aOff + m * 1024);
        #pragma unroll
        for (int n = 0; n < 4; ++n)
            b_[n] = *(const short8*)(base + bOff + n * 1024);
        if (mode == 0) { STAGE(tn, sl2); VM3; }
        else if (mode == 1) { VM0; }
        FENCE(); BAR; FENCE();
        __builtin_amdgcn_s_setprio(1);
        #pragma unroll
        for (int m = 0; m < 4; ++m)
            #pragma unroll
            for (int n = 0; n < 4; ++n)
                acc[m][n] = __builtin_amdgcn_mfma_f32_16x16x32_bf16(
                    a_[m], b_[n], acc[m][n], 0, 0, 0);
        __builtin_amdgcn_s_setprio(0);
        FENCE(); BAR; FENCE();
    };

    // prologue: stage tiles 0,1 -> slots 0,1; VM3 lands tile 0
    STAGE(0, 0);
    STAGE(1, 1);
    VM3; FENCE(); BAR; FENCE();

    int sl = 0, sl2 = 2;
    for (int t = 0; t < nt - 2; ++t) {
        PHASE(sl, t + 2, sl2, 0);
        sl = (sl == 2) ? 0 : sl + 1;
        sl2 = (sl2 == 2) ? 0 : sl2 + 1;
    }
    PHASE(sl, 0, 0, 1);                  // drain last stage (VM0)
    sl = (sl == 2) ? 0 : sl + 1;
    PHASE(sl, 0, 0, 2);                  // final tile, no waits

    #pragma unroll
    for (int m = 0; m < 4; ++m) {
        const int row = bm + wr * 64 + m * 16 + l4 * 4;
        #pragma unroll
        for (int n = 0; n < 4; ++n) {
            const int col = bn + wc * 64 + n * 16 + l15;
            const float bv = (grp == 2) ? gb0[col] : 0.f;
            #pragma unroll
            for (int r = 0; r < 4; ++r) {
                float v = acc[m][n][r] + bv;
                if (grp == 2) v = fmaxf(v, 0.f);
                C[(long)(row + r) * ldc + col] = __float2bfloat16(v);
            }
        }
    }
}

// ===== tail_plus v2: W2 read direct from L2 (no LDS stage) -> 34.5 KB LDS,
// 4 blocks/CU. [0,2048) local tail, [2048,2112) Tg, [2112,2176) Ty =========
__global__ __launch_bounds__(256) void tail_plus(
    const __hip_bfloat16* __restrict__ Yp, const __hip_bfloat16* __restrict__ Mq,
    const float* __restrict__ bin, const short* __restrict__ W2s,
    const float* __restrict__ b2, const float* __restrict__ w3,
    const float* __restrict__ b3, double* __restrict__ acc,
    const short* __restrict__ H0b, const short* __restrict__ WgTb,
    __hip_bfloat16* __restrict__ Tgb,
    const short* __restrict__ ybs, const short* __restrict__ l0ws,
    __hip_bfloat16* __restrict__ Tyb)
{
    __shared__ __align__(16) char smem[35328];
    const int bid = blockIdx.x;
    const int tid = threadIdx.x;
    const int lane = tid & 63;
    const int l15 = lane & 15, l4 = lane >> 4;

    if (bid >= 2048) {
        const int sel = bid - 2048;
        const short* Ain = (sel < 64) ? H0b : ybs;
        const short* Bin = (sel < 64) ? WgTb : l0ws;
        __hip_bfloat16* Co = (sel < 64) ? Tgb : Tyb;
        short* As = (short*)smem;
        short* Bs = (short*)(smem + 16384);
        const int w = tid >> 6;
        const int wr = w >> 1, wc = w & 1;
        const int bm = (sel & 63) * 128;
        const int srow = lane >> 3;
        const int gsrc = (lane & 7) ^ srow;

        f32x4 a4[4][4] = {};
        for (int k0 = 0; k0 < 1024; k0 += 64) {
            #pragma unroll
            for (int s = 0; s < 4; ++s) {
                const int rrel = s * 32 + w * 8 + srow;
                gll16(Ain + (long)(bm + rrel) * 1024 + k0 + gsrc * 8,
                      As + (s * 32 + w * 8) * 64);
                gll16(Bin + (long)rrel * 1024 + k0 + gsrc * 8,
                      Bs + (s * 32 + w * 8) * 64);
            }
            __syncthreads();
            #pragma unroll
            for (int st = 0; st < 2; ++st) {
                const int gr = (st * 4 + l4) ^ (l15 & 7);
                short8 a[4], b[4];
                #pragma unroll
                for (int m = 0; m < 4; ++m)
                    a[m] = *(const short8*)&As[(wr * 64 + m * 16 + l15) * 64 + gr * 8];
                #pragma unroll
                for (int n = 0; n < 4; ++n)
                    b[n] = *(const short8*)&Bs[(wc * 64 + n * 16 + l15) * 64 + gr * 8];
                #pragma unroll
                for (int m = 0; m < 4; ++m)
                    #pragma unroll
                    for (int n = 0; n < 4; ++n)
                        a4[m][n] = __builtin_amdgcn_mfma_f32_16x16x32_bf16(a[m], b[n], a4[m][n], 0, 0, 0);
            }
            __syncthreads();
        }
        #pragma unroll
        for (int m = 0; m < 4; ++m) {
            int row = bm + (w >> 1) * 64 + m * 16 + l4 * 4;
            #pragma unroll
            for (int n = 0; n < 4; ++n) {
                int col = (w & 1) * 64 + n * 16 + l15;
                #pragma unroll
                for (int r = 0; r < 4; ++r)
                    Co[(long)(row + r) * 128 + col] = __float2bfloat16(a4[m][n][r]);
            }
        }
        return;
    }

    const int wkid = (bid & 7) * 256 + (bid >> 3);
    const int e = wkid & 15;
    const int b0 = (wkid >> 4) * 64;
    const int cbase = e * 128;
    const int wid = tid >> 6;
    const int side = wid >> 1;
    const int wr = wid & 1;
    const int widthIn = 2048;

    short* h1 = (short*)smem;                  // 32 KB
    float* bins = (float*)(smem + 32768);
    float* b2s  = (float*)(smem + 33280);
    float* w3s  = (float*)(smem + 33792);
    float* red  = (float*)(smem + 34304);

    const short* W2e = W2s + (long)e * 16384;  // L2-resident, read direct
    if (tid < 128) {
        bins[tid] = bin[cbase + tid];
        b2s[tid]  = b2[cbase + tid];
        w3s[tid]  = w3[cbase + tid];
    }
    __syncthreads();

    const short* Ys = (const short*)Yp;
    const short* Ms = (const short*)Mq;
    #pragma unroll
    for (int c = 0; c < 4; ++c) {
        int chunk = c * 256 + tid;
        int row = chunk >> 4, kc = chunk & 15;
        short8 yv = *(const short8*)&Ys[(long)(b0 + row) * widthIn + cbase + kc * 8];
        float yf[8];
        #pragma unroll
        for (int j = 0; j < 8; ++j) yf[j] = bf2f(yv[j]) + bins[kc * 8 + j];
        int dst = row * 128 + (kc ^ (row & 7)) * 8;
        #pragma unroll
        for (int s = 0; s < 2; ++s) {
            int rowm = (b0 + row + s) & (B_ROWS - 1);
            short8 mv = *(const short8*)&Ms[(long)rowm * widthIn + cbase + kc * 8];
            union { short8 v; short sh[8]; } o;
            #pragma unroll
            for (int j = 0; j < 8; ++j)
                o.sh[j] = f2bf_s(fmaxf(yf[j] + bf2f(mv[j]), 0.f));
            *(short8*)&h1[s * 8192 + dst] = o.v;
        }
    }
    __syncthreads();

    f32x4 accv[2][8] = {};
    #pragma unroll
    for (int st = 0; st < 4; ++st) {
        short8 a[2], b[8];
        #pragma unroll
        for (int m = 0; m < 2; ++m) {
            int row = wr * 32 + m * 16 + l15;
            int ch = (st * 4 + l4) ^ (row & 7);
            a[m] = *(const short8*)&h1[side * 8192 + row * 128 + ch * 8];
        }
        #pragma unroll
        for (int n = 0; n < 8; ++n) {
            int col = n * 16 + l15;
            int ch = (st * 4 + l4) ^ (col & 7);
            b[n] = *(const short8*)&W2e[col * 128 + ch * 8];
        }
        #pragma unroll
        for (int m = 0; m < 2; ++m)
            #pragma unroll
            for (int n = 0; n < 8; ++n)
                accv[m][n] = __builtin_amdgcn_mfma_f32_16x16x32_bf16(a[m], b[n], accv[m][n], 0, 0, 0);
    }

    float p[2][4] = {};
    #pragma unroll
    for (int m = 0; m < 2; ++m)
        #pragma unroll
        for (int n = 0; n < 8; ++n) {
            int colL = n * 16 + l15;
            float bb = b2s[colL], ww = w3s[colL];
            #pragma unroll
            for (int r = 0; r < 4; ++r) {
                float h2 = fmaxf(accv[m][n][r] + bb, 0.f);
                p[m][r] = fmaf(h2, ww, p[m][r]);
            }
        }
    #pragma unroll
    for (int m = 0; m < 2; ++m)
        #pragma unroll
        for (int r = 0; r < 4; ++r)
            #pragma unroll
            for (int off = 1; off < 16; off <<= 1)
                p[m][r] += __shfl_xor(p[m][r], off, 64);

    float mysum = 0.f;
    if (l15 == 0) {
        float bb = b3[e];
        #pragma unroll
        for (int m = 0; m < 2; ++m)
            #pragma unroll
            for (int r = 0; r < 4; ++r) {
                float s = p[m][r] + bb;
                mysum += softplus_f(side ? s : -s);
            }
    }
    red[tid] = mysum;
    __syncthreads();
    for (int s2 = 128; s2 > 0; s2 >>= 1) {
        if (tid < s2) red[tid] += red[tid + s2];
        __syncthreads();
    }
    if (tid == 0) atomicAdd(acc, (double)red[0]);
}

// ---------- global tail + fused finalize (last-block pattern) --------------
__global__ __launch_bounds__(256) void tail_mfma(
    const __hip_bfloat16* __restrict__ Yp, const __hip_bfloat16* __restrict__ Mq,
    const float* __restrict__ bin,
    const short* __restrict__ W2s,
    const float* __restrict__ b2, const float* __restrict__ w3,
    const float* __restrict__ b3,
    int widthIn, double* __restrict__ acc, int* __restrict__ counter,
    float* __restrict__ out)
{
    const int b0 = blockIdx.x * 64;
    const int e = blockIdx.y;
    const int cbase = e * 128;
    const int tid = threadIdx.x;
    const int lane = tid & 63;
    const int wid = tid >> 6;
    const int side = wid >> 1;
    const int wr = wid & 1;

    __shared__ __align__(16) short h1[2 * 64 * 128];
    __shared__ __align__(16) short Bs[128 * 128];
    __shared__ float bins[128], b2s[128], w3s[128];
    __shared__ float red[256];

    const short* W2e = W2s + (long)e * 16384;
    #pragma unroll
    for (int l = 0; l < 8; ++l) {
        int cb = (l * 4 + wid) * 64;
        gll16(W2e + (long)(cb + lane) * 8, &Bs[cb * 8]);
    }
    if (tid < 128) {
        bins[tid] = bin[cbase + tid];
        b2s[tid]  = b2[cbase + tid];
        w3s[tid]  = w3[cbase + tid];
    }
    __syncthreads();

    const short* Ys = (const short*)Yp;
    const short* Ms = (const short*)Mq;
    #pragma unroll
    for (int c = 0; c < 4; ++c) {
        int chunk = c * 256 + tid;
        int row = chunk >> 4, kc = chunk & 15;
        short8 yv = *(const short8*)&Ys[(long)(b0 + row) * widthIn + cbase + kc * 8];
        float yf[8];
        #pragma unroll
        for (int j = 0; j < 8; ++j) yf[j] = bf2f(yv[j]) + bins[kc * 8 + j];
        int dst = row * 128 + (kc ^ (row & 7)) * 8;
        #pragma unroll
        for (int s = 0; s < 2; ++s) {
            int rowm = (b0 + row + s) & (B_ROWS - 1);
            short8 mv = *(const short8*)&Ms[(long)rowm * widthIn + cbase + kc * 8];
            union { short8 v; short sh[8]; } o;
            #pragma unroll
            for (int j = 0; j < 8; ++j)
                o.sh[j] = f2bf_s(fmaxf(yf[j] + bf2f(mv[j]), 0.f));
            *(short8*)&h1[s * 8192 + dst] = o.v;
        }
    }
    __syncthreads();

    const int l15 = lane & 15, l4 = lane >> 4;
    f32x4 accv[2][8] = {};
    #pragma unroll
    for (int st = 0; st < 4; ++st) {
        short8 a[2], b[8];
        #pragma unroll
        for (int m = 0; m < 2; ++m) {
            int row = wr * 32 + m * 16 + l15;
            int ch = (st * 4 + l4) ^ (row & 7);
            a[m] = *(const short8*)&h1[side * 8192 + row * 128 + ch * 8];
        }
        #pragma unroll
        for (int n = 0; n < 8; ++n) {
            int col = n * 16 + l15;
            int ch = (st * 4 + l4) ^ (col & 7);
            b[n] = *(const short8*)&Bs[col * 128 + ch * 8];
        }
        #pragma unroll
        for (int m = 0; m < 2; ++m)
            #pragma unroll
            for (int n = 0; n < 8; ++n)
                accv[m][n] = __builtin_amdgcn_mfma_f32_16x16x32_bf16(a[m], b[n], accv[m][n], 0, 0, 0);
    }

    float p[2][4] = {};
    #pragma unroll
    for (int m = 0; m < 2; ++m)
        #pragma unroll
        for (int n = 0; n < 8; ++n) {
            int colL = n * 16 + l15;
            float bb = b2s[colL], ww = w3s[colL];
            #pragma unroll
            for (int r = 0; r < 4; ++r) {
                float h2 = fmaxf(accv[m][n][r] + bb, 0.f);
                p[m][r] = fmaf(h2, ww, p[m][r]);
            }
        }
    #pragma unroll
    for (int m = 0; m < 2; ++m)
        #pragma unroll
        for (int r = 0; r < 4; ++r)
            #pragma unroll
            for (int off = 1; off < 16; off <<= 1)
                p[m][r] += __shfl_xor(p[m][r], off, 64);

    float mysum = 0.f;
    if (l15 == 0) {
        float bb = b3[e];
        #pragma unroll
        for (int m = 0; m < 2; ++m)
            #pragma unroll
            for (int r = 0; r < 4; ++r) {
                float s = p[m][r] + bb;
                mysum += softplus_f(side ? s : -s);
            }
    }
    red[tid] = mysum;
    __syncthreads();
    for (int s2 = 128; s2 > 0; s2 >>= 1) {
        if (tid < s2) red[tid] += red[tid + s2];
        __syncthreads();
    }
    if (tid == 0) {
        atomicAdd(acc + 1, (double)red[0]);
        __threadfence();
        int old = atomicAdd(counter, 1);
        if (old == (int)(gridDim.x * gridDim.y) - 1) {
            double a0 = atomicAdd(acc + 0, 0.0);
            double a1 = atomicAdd(acc + 1, 0.0);
            out[0] = (float)(a0 / (8192.0 * 16.0) + 0.5 * a1 / 8192.0);
        }
    }
}

extern "C" void kernel_launch(void* const* d_in, const int* in_sizes, int n_in,
                              void* d_out, int out_size, void* d_ws, size_t ws_size,
                              hipStream_t stream)
{
    const float* y   = (const float*)d_in[0];
    const float* M   = (const float*)d_in[1];
    const float* gw0 = (const float*)d_in[2];
    const float* gb0 = (const float*)d_in[3];
    const float* gw1 = (const float*)d_in[4];
    const float* gb1 = (const float*)d_in[5];
    const float* l0w = (const float*)d_in[6];
    const float* l0b = (const float*)d_in[7];
    const float* l1w = (const float*)d_in[8];
    const float* l1b = (const float*)d_in[9];
    const float* l2w = (const float*)d_in[10];
    const float* l2b = (const float*)d_in[11];
    const float* lW1 = (const float*)d_in[12];
    const float* lb1 = (const float*)d_in[13];
    const float* lW2 = (const float*)d_in[14];
    const float* lb2 = (const float*)d_in[15];
    const float* lW3 = (const float*)d_in[16];
    const float* lb3 = (const float*)d_in[17];

    // ---- workspace layout (~127 MB) ----
    char* w = (char*)d_ws;
    double* acc = (double*)w;
    int* counter = (int*)(w + 16);
    float* bing = (float*)(w + 256);
    const size_t MB = 1u << 20;
    __hip_bfloat16* Y1b  = (__hip_bfloat16*)(w + 4096);             // 32 MB
    __hip_bfloat16* Mpb  = (__hip_bfloat16*)(w + 4096 + 32 * MB);   // 32 MB
    __hip_bfloat16* H0b  = (__hip_bfloat16*)(w + 4096 + 64 * MB);   // 16 MB
    short*          Mt2  = (short*)(w + 4096 + 80 * MB);            // 16 MB
    __hip_bfloat16* yb   = (__hip_bfloat16*)(w + 4096 + 96 * MB);   // 16 MB
    __hip_bfloat16* W1yt = (__hip_bfloat16*)(w + 4096 + 112 * MB);  // 4 MB
    __hip_bfloat16* W0p  = (__hip_bfloat16*)(w + 4096 + 118 * MB);  // 2 MB
    __hip_bfloat16* l0wyt = (__hip_bfloat16*)(w + 4096 + 120 * MB); // 256 KB
    short* W2sb = (short*)(w + 4096 + 120 * MB + 512 * 1024);       // 512 KB
    short* L1ws = (short*)(w + 4096 + 121 * MB);                    // 32 KB
    __hip_bfloat16* WgTb = (__hip_bfloat16*)(w + 4096 + 121 * MB + 512 * 1024); // 256 KB
    short* W1m2 = (short*)(w + 4096 + 122 * MB);                    // 512 KB
    __hip_bfloat16* Tyb = (__hip_bfloat16*)(w + 4096 + 123 * MB);   // 2 MB
    __hip_bfloat16* Tgb = (__hip_bfloat16*)(w + 4096 + 125 * MB);   // 2 MB
    // WgT split-K f32 partials: 4 MB scratch overlaying Tyb+Tgb (free until
    // tail_plus; consumed by gemm3s reduce blocks -> WgTb, stream-ordered)
    float* wgtp = (float*)(w + 4096 + 123 * MB);

    dim3 blk(256);

    prep_all<<<dim3(2944), blk, 0, stream>>>(
        y, M, lW1, gw0, l0w, gw1,
        yb, Mt2, W1yt, W1m2, W0p, l0wyt, wgtp);

    gemm3s<<<dim3(1306), dim3(512), 0, stream>>>(
        (const short*)yb, (const short*)W1yt, Y1b,
        Mt2, W1m2, Mpb,
        (const short*)W0p, gb0, H0b,
        wgtp, WgTb,
        l0w, l0b, gb1, lW2, l1w, bing, W2sb, L1ws,
        acc, counter);

    tail_plus<<<dim3(2176), blk, 0, stream>>>(
        Y1b, Mpb, lb1, W2sb, lb2, lW3, lb3, acc,
        (const short*)H0b, (const short*)WgTb, Tgb,
        (const short*)yb, (const short*)l0wyt, Tyb);

    tail_mfma<<<dim3(128, 1), blk, 0, stream>>>(
        Tyb, Tgb, bing, L1ws, l1b, l2w, l2b, 128, acc, counter,
        (float*)d_out);
}